// Round 1
// baseline (747.368 us; speedup 1.0000x reference)
//
#include <hip/hip_runtime.h>
#include <math.h>

#define DF 768      // feature dim
#define NN 64       // nodes
#define DN 832      // batch row stride (D + N)
#define LDH 776     // h row-major LDS row stride (halves), pad breaks bank conflicts
#define LDT 72      // hpT / attn LDS row stride (halves)
#define NEG_SLOPE 0.2f

typedef _Float16 f16;
typedef __attribute__((ext_vector_type(8))) _Float16 f16x8;
typedef __attribute__((ext_vector_type(4))) float f32x4;

__device__ __forceinline__ float tanh_fast(float x) {
  // exact identity; __expf is HW v_exp_f32 (abs err ~1e-7 on th)
  return 1.0f - 2.0f / (__expf(2.0f * x) + 1.0f);
}

// ---------- prep: transpose w (768x768 fp32) -> wT[o][k] f16 ----------
__global__ void prep_wT(const float* __restrict__ w, f16* __restrict__ wT) {
  __shared__ float tile[32][33];
  int bx = blockIdx.x % 24;   // o tile
  int by = blockIdx.x / 24;   // k tile
  int tx = threadIdx.x & 31;
  int ty = threadIdx.x >> 5;  // 0..7
#pragma unroll
  for (int rr = 0; rr < 4; ++rr)
    tile[ty + rr * 8][tx] = w[(size_t)(by * 32 + ty + rr * 8) * DF + bx * 32 + tx];
  __syncthreads();
#pragma unroll
  for (int rr = 0; rr < 4; ++rr)
    wT[(size_t)(bx * 32 + ty + rr * 8) * DF + by * 32 + tx] = (f16)tile[tx][ty + rr * 8];
}

// ---------- prep: mlp_w fp32 -> f16 (same row-major (d, j) layout) ----------
__global__ void prep_mlp(const float* __restrict__ mw, f16* __restrict__ mwh) {
  int i = blockIdx.x * 256 + threadIdx.x;
  mwh[i] = (f16)mw[i];
}

// ---------- fused 2-layer GAT: one workgroup per batch item ----------
__global__ __launch_bounds__(512, 2) void gat_fused(
    const float* __restrict__ batch,
    const f16* __restrict__ wT,          // (768 x 768), wT[o][k] = w[k][o]
    const float* __restrict__ a_src,
    const float* __restrict__ a_dst,
    const float* __restrict__ gat_bias,
    f16* __restrict__ cneighW)           // (512 x 768) l2normed h[:,0]
{
  // Hbuf doubles as: h row-major (64 x LDH) and hpT (768 x LDT)
  __shared__ f16 Hbuf[DF * LDT];              // 110592 B
  __shared__ f16 attnB[NN * LDT];             // 9216 B
  __shared__ float asrcL[DF], adstL[DF], biasL[DF];
  __shared__ float srcv[NN], dstv[NN];
  __shared__ float redS[8 * NN], redD[8 * NN];
  __shared__ unsigned long long maskRow[NN];
  __shared__ float attn0[NN];
  __shared__ float h2row[DF];
  __shared__ float ssqred[8];

  const int tid  = threadIdx.x;
  const int lane = tid & 63;
  const int wv   = tid >> 6;     // wave 0..7
  const int l16  = lane & 15;
  const int quad = lane >> 4;    // 0..3
  const int b    = blockIdx.x;
  const int cb   = wv * 96;      // this wave's column base (8 waves x 96 = 768)

  const float* bb = batch + (size_t)b * (NN * DN);

  // params -> LDS
  for (int i = tid; i < DF; i += 512) {
    asrcL[i] = a_src[i];
    adstL[i] = a_dst[i];
    biasL[i] = gat_bias[i];
  }
  // stage h0 = features (fp32 -> f16), row-major
  for (int i = tid; i < NN * DF; i += 512) {
    int r = i / DF, c = i - r * DF;
    Hbuf[r * LDH + c] = (f16)bb[r * DN + c];
  }
  // adjacency mask via ballot: wave wv builds rows 8*wv..8*wv+7
#pragma unroll
  for (int r = 0; r < 8; ++r) {
    int n = wv * 8 + r;
    float av = bb[n * DN + DF + lane];
    unsigned long long m = __ballot(av != 0.0f);
    if (lane == 0) maskRow[n] = m | (1ULL << n);   // eye
  }
  __syncthreads();

  for (int layer = 0; layer < 2; ++layer) {
    // ================= GEMM1: hp = h @ w =================
    f32x4 acc[4][6];
#pragma unroll
    for (int rt = 0; rt < 4; ++rt)
#pragma unroll
      for (int ct = 0; ct < 6; ++ct)
        acc[rt][ct] = (f32x4){0.f, 0.f, 0.f, 0.f};

    // B-fragment prefetch pipeline (global, L2-hot)
    f16x8 bfr[6], bnx[6];
#pragma unroll
    for (int ct = 0; ct < 6; ++ct)
      bfr[ct] = *(const f16x8*)&wT[(size_t)(cb + ct * 16 + l16) * DF + quad * 8];

    for (int k0 = 0; k0 < DF; k0 += 32) {
      f16x8 af[4];
#pragma unroll
      for (int rt = 0; rt < 4; ++rt)
        af[rt] = *(const f16x8*)&Hbuf[(rt * 16 + l16) * LDH + k0 + quad * 8];
      if (k0 + 32 < DF) {
#pragma unroll
        for (int ct = 0; ct < 6; ++ct)
          bnx[ct] = *(const f16x8*)&wT[(size_t)(cb + ct * 16 + l16) * DF + (k0 + 32) + quad * 8];
      }
#pragma unroll
      for (int ct = 0; ct < 6; ++ct)
#pragma unroll
        for (int rt = 0; rt < 4; ++rt)
          acc[rt][ct] = __builtin_amdgcn_mfma_f32_16x16x32_f16(af[rt], bfr[ct], acc[rt][ct], 0, 0, 0);
#pragma unroll
      for (int ct = 0; ct < 6; ++ct) bfr[ct] = bnx[ct];
    }
    __syncthreads();   // all h reads done

    // write hp transposed: hpT[o][m]  (C layout: row=rt*16+quad*4+i, col=cb+ct*16+l16)
#pragma unroll
    for (int rt = 0; rt < 4; ++rt)
#pragma unroll
      for (int ct = 0; ct < 6; ++ct)
#pragma unroll
        for (int i = 0; i < 4; ++i) {
          int row = rt * 16 + quad * 4 + i;
          int col = cb + ct * 16 + l16;
          Hbuf[col * LDT + row] = (f16)acc[rt][ct][i];
        }
    __syncthreads();

    // ================= src/dst: th = tanh(hp), dot with a_src/a_dst =================
    {
      float s = 0.f, d = 0.f;
      int m = lane;
      int o0 = wv * 96;
      for (int o = o0; o < o0 + 96; ++o) {
        float t = tanh_fast((float)Hbuf[o * LDT + m]);
        s += t * asrcL[o];
        d += t * adstL[o];
      }
      redS[wv * 64 + m] = s;
      redD[wv * 64 + m] = d;
    }
    __syncthreads();
    if (tid < 64) {
      float s = 0.f, d = 0.f;
#pragma unroll
      for (int q = 0; q < 8; ++q) { s += redS[q * 64 + tid]; d += redD[q * 64 + tid]; }
      srcv[tid] = s;
      dstv[tid] = d;
    }
    __syncthreads();

    if (layer == 0) {
      // ---- full attention: wave wv does rows 8*wv..8*wv+7, lane = neighbor m ----
      for (int r = 0; r < 8; ++r) {
        int n = wv * 8 + r;
        float logit = srcv[n] + dstv[lane];
        logit = logit >= 0.f ? logit : NEG_SLOPE * logit;
        bool ok = (maskRow[n] >> lane) & 1ULL;
        float v = ok ? logit : -1e30f;
        float mx = v;
#pragma unroll
        for (int off = 32; off > 0; off >>= 1) mx = fmaxf(mx, __shfl_xor(mx, off, 64));
        float e = ok ? __expf(v - mx) : 0.f;
        float sm = e;
#pragma unroll
        for (int off = 32; off > 0; off >>= 1) sm += __shfl_xor(sm, off, 64);
        attnB[n * LDT + lane] = (f16)(e / sm);
      }
      __syncthreads();

      // ---- GEMM2: h_new = attn @ hp  (A=attnB row-major, B=hpT) ----
      f32x4 acc2[4][6];
#pragma unroll
      for (int rt = 0; rt < 4; ++rt)
#pragma unroll
        for (int ct = 0; ct < 6; ++ct)
          acc2[rt][ct] = (f32x4){0.f, 0.f, 0.f, 0.f};
#pragma unroll
      for (int k0 = 0; k0 < NN; k0 += 32) {
        f16x8 af[4];
#pragma unroll
        for (int rt = 0; rt < 4; ++rt)
          af[rt] = *(const f16x8*)&attnB[(rt * 16 + l16) * LDT + k0 + quad * 8];
#pragma unroll
        for (int ct = 0; ct < 6; ++ct) {
          f16x8 bf = *(const f16x8*)&Hbuf[(cb + ct * 16 + l16) * LDT + k0 + quad * 8];
#pragma unroll
          for (int rt = 0; rt < 4; ++rt)
            acc2[rt][ct] = __builtin_amdgcn_mfma_f32_16x16x32_f16(af[rt], bf, acc2[rt][ct], 0, 0, 0);
        }
      }
      __syncthreads();  // all hpT reads done before overwriting Hbuf
      // h_new (+bias) -> Hbuf row-major (next layer's h)
#pragma unroll
      for (int rt = 0; rt < 4; ++rt)
#pragma unroll
        for (int ct = 0; ct < 6; ++ct)
#pragma unroll
          for (int i = 0; i < 4; ++i) {
            int row = rt * 16 + quad * 4 + i;
            int col = cb + ct * 16 + l16;
            Hbuf[row * LDH + col] = (f16)(acc2[rt][ct][i] + biasL[col]);
          }
      __syncthreads();
    } else {
      // ---- layer 2: only row 0 of h_new is ever used ----
      if (wv == 0) {
        float logit = srcv[0] + dstv[lane];
        logit = logit >= 0.f ? logit : NEG_SLOPE * logit;
        bool ok = (maskRow[0] >> lane) & 1ULL;
        float v = ok ? logit : -1e30f;
        float mx = v;
#pragma unroll
        for (int off = 32; off > 0; off >>= 1) mx = fmaxf(mx, __shfl_xor(mx, off, 64));
        float e = ok ? __expf(v - mx) : 0.f;
        float sm = e;
#pragma unroll
        for (int off = 32; off > 0; off >>= 1) sm += __shfl_xor(sm, off, 64);
        attn0[lane] = e / sm;   // keep fp32
      }
      __syncthreads();
      // h2_0[o] = bias[o] + sum_m attn0[m] * hp[m][o]
      for (int o = tid; o < DF; o += 512) {
        float a = biasL[o];
#pragma unroll 8
        for (int m2 = 0; m2 < NN; ++m2) a += attn0[m2] * (float)Hbuf[o * LDT + m2];
        h2row[o] = a;
      }
      __syncthreads();
      // l2norm of h2_0 -> cneighW
      float p = 0.f;
      for (int o = tid; o < DF; o += 512) p += h2row[o] * h2row[o];
#pragma unroll
      for (int off = 32; off > 0; off >>= 1) p += __shfl_xor(p, off, 64);
      if (lane == 0) ssqred[wv] = p;
      __syncthreads();
      if (tid == 0) {
        float ss = 0.f;
#pragma unroll
        for (int q = 0; q < 8; ++q) ss += ssqred[q];
        ssqred[0] = 1.0f / fmaxf(sqrtf(ss), 1e-12f);
      }
      __syncthreads();
      float scale = ssqred[0];
      for (int o = tid; o < DF; o += 512)
        cneighW[(size_t)b * DF + o] = (f16)(h2row[o] * scale);
    }
  }
}

// ---------- final: out = [center | cneigh] @ mlp_w.T + mlp_b, then row l2norm ----------
__global__ __launch_bounds__(512, 2) void final_mlp(
    const float* __restrict__ batch,
    const f16* __restrict__ cneighW,
    const f16* __restrict__ mwh,         // (768 x 1536) row-major (d, j)
    const float* __restrict__ mlp_b,
    float* __restrict__ out)
{
  __shared__ f16 Abuf[16 * LDT];   // 16 batch rows x 64-k chunk
  __shared__ float nrm[16];
  const int tid  = threadIdx.x;
  const int lane = tid & 63;
  const int wv   = tid >> 6;
  const int l16  = lane & 15;
  const int quad = lane >> 4;
  const int b0   = blockIdx.x * 16;
  const int cb   = wv * 96;

  f32x4 acc[6];
#pragma unroll
  for (int ct = 0; ct < 6; ++ct) acc[ct] = (f32x4){0.f, 0.f, 0.f, 0.f};

  for (int k0 = 0; k0 < 2 * DF; k0 += 64) {
    __syncthreads();
    // stage A chunk: 16 rows x 64 k (center fp32 or cneigh f16)
    for (int i = tid; i < 16 * 64; i += 512) {
      int r = i >> 6, c = i & 63;
      int j = k0 + c;
      float v;
      if (j < DF) v = batch[(size_t)(b0 + r) * (NN * DN) + j];        // node-0 features
      else        v = (float)cneighW[(size_t)(b0 + r) * DF + (j - DF)];
      Abuf[r * LDT + c] = (f16)v;
    }
    __syncthreads();
#pragma unroll
    for (int ks = 0; ks < 64; ks += 32) {
      f16x8 af = *(const f16x8*)&Abuf[l16 * LDT + ks + quad * 8];
#pragma unroll
      for (int ct = 0; ct < 6; ++ct) {
        f16x8 bf = *(const f16x8*)&mwh[(size_t)(cb + ct * 16 + l16) * (2 * DF) + k0 + ks + quad * 8];
        acc[ct] = __builtin_amdgcn_mfma_f32_16x16x32_f16(af, bf, acc[ct], 0, 0, 0);
      }
    }
  }
  if (tid < 16) nrm[tid] = 0.f;
  __syncthreads();
  float vals[6][4];
  float part[4] = {0.f, 0.f, 0.f, 0.f};
#pragma unroll
  for (int ct = 0; ct < 6; ++ct) {
    float bv = mlp_b[cb + ct * 16 + l16];
#pragma unroll
    for (int i = 0; i < 4; ++i) {
      float v = acc[ct][i] + bv;
      vals[ct][i] = v;
      part[i] += v * v;
    }
  }
#pragma unroll
  for (int i = 0; i < 4; ++i) {
    float p = part[i];
    p += __shfl_xor(p, 1, 64);
    p += __shfl_xor(p, 2, 64);
    p += __shfl_xor(p, 4, 64);
    p += __shfl_xor(p, 8, 64);
    if (l16 == 0) atomicAdd(&nrm[quad * 4 + i], p);
  }
  __syncthreads();
  float sc[4];
#pragma unroll
  for (int i = 0; i < 4; ++i) sc[i] = 1.0f / fmaxf(sqrtf(nrm[quad * 4 + i]), 1e-12f);
#pragma unroll
  for (int ct = 0; ct < 6; ++ct)
#pragma unroll
    for (int i = 0; i < 4; ++i) {
      int row = quad * 4 + i;
      int col = cb + ct * 16 + l16;
      out[(size_t)(b0 + row) * DF + col] = vals[ct][i] * sc[i];
    }
}

extern "C" void kernel_launch(void* const* d_in, const int* in_sizes, int n_in,
                              void* d_out, int out_size, void* d_ws, size_t ws_size,
                              hipStream_t stream) {
  const float* batch    = (const float*)d_in[0];  // (512, 64, 832)
  const float* w        = (const float*)d_in[1];  // (1, 768, 768)
  const float* a_src    = (const float*)d_in[2];  // (1, 768, 1)
  const float* a_dst    = (const float*)d_in[3];  // (1, 768, 1)
  const float* gat_bias = (const float*)d_in[4];  // (768,)
  const float* mlp_w    = (const float*)d_in[5];  // (768, 1536)
  const float* mlp_b    = (const float*)d_in[6];  // (768,)
  float* out = (float*)d_out;

  // workspace layout (f16): wT 768x768 | mlp_w 768x1536 | cneigh 512x768
  f16* wT      = (f16*)d_ws;
  f16* mwh     = wT + (size_t)DF * DF;
  f16* cneighW = mwh + (size_t)DF * 2 * DF;

  prep_wT<<<dim3(24 * 24), dim3(256), 0, stream>>>(w, wT);
  prep_mlp<<<dim3((DF * 2 * DF) / 256), dim3(256), 0, stream>>>(mlp_w, mwh);
  gat_fused<<<dim3(512), dim3(512), 0, stream>>>(batch, wT, a_src, a_dst, gat_bias, cneighW);
  final_mlp<<<dim3(32), dim3(512), 0, stream>>>(batch, cneighW, mwh, mlp_b, out);
}

// Round 2
// 743.138 us; speedup vs baseline: 1.0057x; 1.0057x over previous
//
#include <hip/hip_runtime.h>
#include <math.h>

#define DF 768      // feature dim
#define NN 64       // nodes
#define DN 832      // batch row stride (D + N)
#define LDH 776     // h row-major LDS row stride (halves), pad breaks bank conflicts
#define LDT 72      // hpT / attn LDS row stride (halves)
#define NEG_SLOPE 0.2f

typedef _Float16 f16;
typedef __attribute__((ext_vector_type(4))) _Float16 f16x4;
typedef __attribute__((ext_vector_type(8))) _Float16 f16x8;
typedef __attribute__((ext_vector_type(4))) float f32x4;

__device__ __forceinline__ float tanh_fast(float x) {
  // exact identity; __expf is HW v_exp_f32 (abs err ~1e-7 on th)
  return 1.0f - 2.0f / (__expf(2.0f * x) + 1.0f);
}

// ---------- prep: transpose w (768x768 fp32) -> wT[o][k] f16 ----------
__global__ void prep_wT(const float* __restrict__ w, f16* __restrict__ wT) {
  __shared__ float tile[32][33];
  int bx = blockIdx.x % 24;   // o tile
  int by = blockIdx.x / 24;   // k tile
  int tx = threadIdx.x & 31;
  int ty = threadIdx.x >> 5;  // 0..7
#pragma unroll
  for (int rr = 0; rr < 4; ++rr)
    tile[ty + rr * 8][tx] = w[(size_t)(by * 32 + ty + rr * 8) * DF + bx * 32 + tx];
  __syncthreads();
#pragma unroll
  for (int rr = 0; rr < 4; ++rr)
    wT[(size_t)(bx * 32 + ty + rr * 8) * DF + by * 32 + tx] = (f16)tile[tx][ty + rr * 8];
}

// ---------- prep: mlp_w fp32 -> f16 (same row-major (d, j) layout) ----------
__global__ void prep_mlp(const float* __restrict__ mw, f16* __restrict__ mwh) {
  int i = blockIdx.x * 256 + threadIdx.x;
  mwh[i] = (f16)mw[i];
}

// ---------- fused 2-layer GAT: one workgroup per batch item ----------
// __launch_bounds__(512, 1): 512 thr = 8 waves = 2 waves/SIMD structurally ->
// hard VGPR cap 256. Round 1 used (512,2) which capped VGPRs at 128 and
// spilled ~60 regs/thread -> 1 GB/dispatch of scratch traffic (WRITE_SIZE
// 524 MB observed). LDS (137 KB) limits residency to 1 block/CU regardless.
__global__ __launch_bounds__(512, 1) void gat_fused(
    const float* __restrict__ batch,
    const f16* __restrict__ wT,          // (768 x 768), wT[o][k] = w[k][o]
    const float* __restrict__ a_src,
    const float* __restrict__ a_dst,
    const float* __restrict__ gat_bias,
    f16* __restrict__ cneighW)           // (512 x 768) l2normed h[:,0]
{
  // Hbuf doubles as: h row-major (64 x LDH) and hpT (768 x LDT)
  __shared__ __align__(16) f16 Hbuf[DF * LDT];   // 110592 B
  __shared__ __align__(16) f16 attnB[NN * LDT];  // 9216 B
  __shared__ float asrcL[DF], adstL[DF], biasL[DF];
  __shared__ float srcv[NN], dstv[NN];
  __shared__ float redS[8 * NN], redD[8 * NN];
  __shared__ unsigned long long maskRow[NN];
  __shared__ float attn0[NN];
  __shared__ float h2row[DF];
  __shared__ float ssqred[8];

  const int tid  = threadIdx.x;
  const int lane = tid & 63;
  const int wv   = tid >> 6;     // wave 0..7
  const int l16  = lane & 15;
  const int quad = lane >> 4;    // 0..3
  const int b    = blockIdx.x;
  const int cb   = wv * 96;      // this wave's column base (8 waves x 96 = 768)

  const float* bb = batch + (size_t)b * (NN * DN);

  // params -> LDS
  for (int i = tid; i < DF; i += 512) {
    asrcL[i] = a_src[i];
    adstL[i] = a_dst[i];
    biasL[i] = gat_bias[i];
  }
  // stage h0 = features (fp32 -> f16), row-major, float4-vectorized
  // NN*DF/4 = 12288 float4 elements; batch row stride 832 floats (16B-aligned)
  for (int i = tid; i < NN * (DF / 4); i += 512) {
    int r = i / (DF / 4), c4 = i - r * (DF / 4);
    float4 v = *(const float4*)&bb[r * DN + c4 * 4];
    f16x4 h4 = {(f16)v.x, (f16)v.y, (f16)v.z, (f16)v.w};
    *(f16x4*)&Hbuf[r * LDH + c4 * 4] = h4;
  }
  // adjacency mask via ballot: wave wv builds rows 8*wv..8*wv+7
#pragma unroll
  for (int r = 0; r < 8; ++r) {
    int n = wv * 8 + r;
    float av = bb[n * DN + DF + lane];
    unsigned long long m = __ballot(av != 0.0f);
    if (lane == 0) maskRow[n] = m | (1ULL << n);   // eye
  }
  __syncthreads();

  for (int layer = 0; layer < 2; ++layer) {
    // ================= GEMM1: hp = h @ w =================
    f32x4 acc[4][6];
#pragma unroll
    for (int rt = 0; rt < 4; ++rt)
#pragma unroll
      for (int ct = 0; ct < 6; ++ct)
        acc[rt][ct] = (f32x4){0.f, 0.f, 0.f, 0.f};

    // B-fragment prefetch pipeline (global, L2-hot)
    f16x8 bfr[6], bnx[6];
#pragma unroll
    for (int ct = 0; ct < 6; ++ct)
      bfr[ct] = *(const f16x8*)&wT[(size_t)(cb + ct * 16 + l16) * DF + quad * 8];

    for (int k0 = 0; k0 < DF; k0 += 32) {
      f16x8 af[4];
#pragma unroll
      for (int rt = 0; rt < 4; ++rt)
        af[rt] = *(const f16x8*)&Hbuf[(rt * 16 + l16) * LDH + k0 + quad * 8];
      if (k0 + 32 < DF) {
#pragma unroll
        for (int ct = 0; ct < 6; ++ct)
          bnx[ct] = *(const f16x8*)&wT[(size_t)(cb + ct * 16 + l16) * DF + (k0 + 32) + quad * 8];
      }
#pragma unroll
      for (int ct = 0; ct < 6; ++ct)
#pragma unroll
        for (int rt = 0; rt < 4; ++rt)
          acc[rt][ct] = __builtin_amdgcn_mfma_f32_16x16x32_f16(af[rt], bfr[ct], acc[rt][ct], 0, 0, 0);
#pragma unroll
      for (int ct = 0; ct < 6; ++ct) bfr[ct] = bnx[ct];
    }
    __syncthreads();   // all h reads done

    // write hp transposed: hpT[o][m]  (C layout: row=rt*16+quad*4+i, col=cb+ct*16+l16)
#pragma unroll
    for (int rt = 0; rt < 4; ++rt)
#pragma unroll
      for (int ct = 0; ct < 6; ++ct)
#pragma unroll
        for (int i = 0; i < 4; ++i) {
          int row = rt * 16 + quad * 4 + i;
          int col = cb + ct * 16 + l16;
          Hbuf[col * LDT + row] = (f16)acc[rt][ct][i];
        }
    __syncthreads();

    // ================= src/dst: th = tanh(hp), dot with a_src/a_dst =================
    {
      float s = 0.f, d = 0.f;
      int m = lane;
      int o0 = wv * 96;
      for (int o = o0; o < o0 + 96; ++o) {
        float t = tanh_fast((float)Hbuf[o * LDT + m]);
        s += t * asrcL[o];
        d += t * adstL[o];
      }
      redS[wv * 64 + m] = s;
      redD[wv * 64 + m] = d;
    }
    __syncthreads();
    if (tid < 64) {
      float s = 0.f, d = 0.f;
#pragma unroll
      for (int q = 0; q < 8; ++q) { s += redS[q * 64 + tid]; d += redD[q * 64 + tid]; }
      srcv[tid] = s;
      dstv[tid] = d;
    }
    __syncthreads();

    if (layer == 0) {
      // ---- full attention: wave wv does rows 8*wv..8*wv+7, lane = neighbor m ----
      for (int r = 0; r < 8; ++r) {
        int n = wv * 8 + r;
        float logit = srcv[n] + dstv[lane];
        logit = logit >= 0.f ? logit : NEG_SLOPE * logit;
        bool ok = (maskRow[n] >> lane) & 1ULL;
        float v = ok ? logit : -1e30f;
        float mx = v;
#pragma unroll
        for (int off = 32; off > 0; off >>= 1) mx = fmaxf(mx, __shfl_xor(mx, off, 64));
        float e = ok ? __expf(v - mx) : 0.f;
        float sm = e;
#pragma unroll
        for (int off = 32; off > 0; off >>= 1) sm += __shfl_xor(sm, off, 64);
        attnB[n * LDT + lane] = (f16)(e / sm);
      }
      __syncthreads();

      // ---- GEMM2: h_new = attn @ hp  (A=attnB row-major, B=hpT) ----
      f32x4 acc2[4][6];
#pragma unroll
      for (int rt = 0; rt < 4; ++rt)
#pragma unroll
        for (int ct = 0; ct < 6; ++ct)
          acc2[rt][ct] = (f32x4){0.f, 0.f, 0.f, 0.f};
#pragma unroll
      for (int k0 = 0; k0 < NN; k0 += 32) {
        f16x8 af[4];
#pragma unroll
        for (int rt = 0; rt < 4; ++rt)
          af[rt] = *(const f16x8*)&attnB[(rt * 16 + l16) * LDT + k0 + quad * 8];
#pragma unroll
        for (int ct = 0; ct < 6; ++ct) {
          f16x8 bf = *(const f16x8*)&Hbuf[(cb + ct * 16 + l16) * LDT + k0 + quad * 8];
#pragma unroll
          for (int rt = 0; rt < 4; ++rt)
            acc2[rt][ct] = __builtin_amdgcn_mfma_f32_16x16x32_f16(af[rt], bf, acc2[rt][ct], 0, 0, 0);
        }
      }
      __syncthreads();  // all hpT reads done before overwriting Hbuf
      // h_new (+bias) -> Hbuf row-major (next layer's h)
#pragma unroll
      for (int rt = 0; rt < 4; ++rt)
#pragma unroll
        for (int ct = 0; ct < 6; ++ct)
#pragma unroll
          for (int i = 0; i < 4; ++i) {
            int row = rt * 16 + quad * 4 + i;
            int col = cb + ct * 16 + l16;
            Hbuf[row * LDH + col] = (f16)(acc2[rt][ct][i] + biasL[col]);
          }
      __syncthreads();
    } else {
      // ---- layer 2: only row 0 of h_new is ever used ----
      if (wv == 0) {
        float logit = srcv[0] + dstv[lane];
        logit = logit >= 0.f ? logit : NEG_SLOPE * logit;
        bool ok = (maskRow[0] >> lane) & 1ULL;
        float v = ok ? logit : -1e30f;
        float mx = v;
#pragma unroll
        for (int off = 32; off > 0; off >>= 1) mx = fmaxf(mx, __shfl_xor(mx, off, 64));
        float e = ok ? __expf(v - mx) : 0.f;
        float sm = e;
#pragma unroll
        for (int off = 32; off > 0; off >>= 1) sm += __shfl_xor(sm, off, 64);
        attn0[lane] = e / sm;   // keep fp32
      }
      __syncthreads();
      // h2_0[o] = bias[o] + sum_m attn0[m] * hp[m][o]
      for (int o = tid; o < DF; o += 512) {
        float a = biasL[o];
#pragma unroll 8
        for (int m2 = 0; m2 < NN; ++m2) a += attn0[m2] * (float)Hbuf[o * LDT + m2];
        h2row[o] = a;
      }
      __syncthreads();
      // l2norm of h2_0 -> cneighW
      float p = 0.f;
      for (int o = tid; o < DF; o += 512) p += h2row[o] * h2row[o];
#pragma unroll
      for (int off = 32; off > 0; off >>= 1) p += __shfl_xor(p, off, 64);
      if (lane == 0) ssqred[wv] = p;
      __syncthreads();
      if (tid == 0) {
        float ss = 0.f;
#pragma unroll
        for (int q = 0; q < 8; ++q) ss += ssqred[q];
        ssqred[0] = 1.0f / fmaxf(sqrtf(ss), 1e-12f);
      }
      __syncthreads();
      float scale = ssqred[0];
      for (int o = tid; o < DF; o += 512)
        cneighW[(size_t)b * DF + o] = (f16)(h2row[o] * scale);
    }
  }
}

// ---------- final: out = [center | cneigh] @ mlp_w.T + mlp_b, then row l2norm ----------
__global__ __launch_bounds__(512, 2) void final_mlp(
    const float* __restrict__ batch,
    const f16* __restrict__ cneighW,
    const f16* __restrict__ mwh,         // (768 x 1536) row-major (d, j)
    const float* __restrict__ mlp_b,
    float* __restrict__ out)
{
  __shared__ f16 Abuf[16 * LDT];   // 16 batch rows x 64-k chunk
  __shared__ float nrm[16];
  const int tid  = threadIdx.x;
  const int lane = tid & 63;
  const int wv   = tid >> 6;
  const int l16  = lane & 15;
  const int quad = lane >> 4;
  const int b0   = blockIdx.x * 16;
  const int cb   = wv * 96;

  f32x4 acc[6];
#pragma unroll
  for (int ct = 0; ct < 6; ++ct) acc[ct] = (f32x4){0.f, 0.f, 0.f, 0.f};

  for (int k0 = 0; k0 < 2 * DF; k0 += 64) {
    __syncthreads();
    // stage A chunk: 16 rows x 64 k (center fp32 or cneigh f16)
    for (int i = tid; i < 16 * 64; i += 512) {
      int r = i >> 6, c = i & 63;
      int j = k0 + c;
      float v;
      if (j < DF) v = batch[(size_t)(b0 + r) * (NN * DN) + j];        // node-0 features
      else        v = (float)cneighW[(size_t)(b0 + r) * DF + (j - DF)];
      Abuf[r * LDT + c] = (f16)v;
    }
    __syncthreads();
#pragma unroll
    for (int ks = 0; ks < 64; ks += 32) {
      f16x8 af = *(const f16x8*)&Abuf[l16 * LDT + ks + quad * 8];
#pragma unroll
      for (int ct = 0; ct < 6; ++ct) {
        f16x8 bf = *(const f16x8*)&mwh[(size_t)(cb + ct * 16 + l16) * (2 * DF) + k0 + ks + quad * 8];
        acc[ct] = __builtin_amdgcn_mfma_f32_16x16x32_f16(af, bf, acc[ct], 0, 0, 0);
      }
    }
  }
  if (tid < 16) nrm[tid] = 0.f;
  __syncthreads();
  float vals[6][4];
  float part[4] = {0.f, 0.f, 0.f, 0.f};
#pragma unroll
  for (int ct = 0; ct < 6; ++ct) {
    float bv = mlp_b[cb + ct * 16 + l16];
#pragma unroll
    for (int i = 0; i < 4; ++i) {
      float v = acc[ct][i] + bv;
      vals[ct][i] = v;
      part[i] += v * v;
    }
  }
#pragma unroll
  for (int i = 0; i < 4; ++i) {
    float p = part[i];
    p += __shfl_xor(p, 1, 64);
    p += __shfl_xor(p, 2, 64);
    p += __shfl_xor(p, 4, 64);
    p += __shfl_xor(p, 8, 64);
    if (l16 == 0) atomicAdd(&nrm[quad * 4 + i], p);
  }
  __syncthreads();
  float sc[4];
#pragma unroll
  for (int i = 0; i < 4; ++i) sc[i] = 1.0f / fmaxf(sqrtf(nrm[quad * 4 + i]), 1e-12f);
#pragma unroll
  for (int ct = 0; ct < 6; ++ct)
#pragma unroll
    for (int i = 0; i < 4; ++i) {
      int row = quad * 4 + i;
      int col = cb + ct * 16 + l16;
      out[(size_t)(b0 + row) * DF + col] = vals[ct][i] * sc[i];
    }
}

extern "C" void kernel_launch(void* const* d_in, const int* in_sizes, int n_in,
                              void* d_out, int out_size, void* d_ws, size_t ws_size,
                              hipStream_t stream) {
  const float* batch    = (const float*)d_in[0];  // (512, 64, 832)
  const float* w        = (const float*)d_in[1];  // (1, 768, 768)
  const float* a_src    = (const float*)d_in[2];  // (1, 768, 1)
  const float* a_dst    = (const float*)d_in[3];  // (1, 768, 1)
  const float* gat_bias = (const float*)d_in[4];  // (768,)
  const float* mlp_w    = (const float*)d_in[5];  // (768, 1536)
  const float* mlp_b    = (const float*)d_in[6];  // (768,)
  float* out = (float*)d_out;

  // workspace layout (f16): wT 768x768 | mlp_w 768x1536 | cneigh 512x768
  f16* wT      = (f16*)d_ws;
  f16* mwh     = wT + (size_t)DF * DF;
  f16* cneighW = mwh + (size_t)DF * 2 * DF;

  prep_wT<<<dim3(24 * 24), dim3(256), 0, stream>>>(w, wT);
  prep_mlp<<<dim3((DF * 2 * DF) / 256), dim3(256), 0, stream>>>(mlp_w, mwh);
  gat_fused<<<dim3(512), dim3(512), 0, stream>>>(batch, wT, a_src, a_dst, gat_bias, cneighW);
  final_mlp<<<dim3(32), dim3(512), 0, stream>>>(batch, cneighW, mwh, mlp_b, out);
}